// Round 1
// baseline (1618.160 us; speedup 1.0000x reference)
//
#include <hip/hip_runtime.h>
#include <stdint.h>

#define B_ 32
#define V_ 4096
#define H_ 1024

typedef __bf16 bf16x8 __attribute__((ext_vector_type(8)));
typedef float f32x4 __attribute__((ext_vector_type(4)));

__device__ __forceinline__ unsigned short f2bf(float x) {
    unsigned int u = __float_as_uint(x);
    u += 0x7fffu + ((u >> 16) & 1u);
    return (unsigned short)(u >> 16);
}

// K1: Wk f32 [o][k] -> bf16 ushort [o][k]
__global__ __launch_bounds__(256) void wk_to_bf16(const float* __restrict__ wk,
                                                  unsigned short* __restrict__ out) {
    int i = (blockIdx.x * 256 + threadIdx.x) * 4;
    float4 f = *(const float4*)(wk + i);
    ushort4 u;
    u.x = f2bf(f.x); u.y = f2bf(f.y); u.z = f2bf(f.z); u.w = f2bf(f.w);
    *(ushort4*)(out + i) = u;
}

// K2: r[b][o] = bias[o] + sum_h query[b][h]*Wq[o][h]   (one wave per (b,o))
__global__ __launch_bounds__(256) void compute_r(const float* __restrict__ query,
                                                 const float* __restrict__ wq,
                                                 const float* __restrict__ bias,
                                                 float* __restrict__ r) {
    int gid = blockIdx.x * 4 + (threadIdx.x >> 6);
    int lane = threadIdx.x & 63;
    int b = gid & 31;       // consecutive waves share the same Wq row -> L2 hit
    int o = gid >> 5;
    const float4* q4 = (const float4*)(query + b * H_);
    const float4* w4 = (const float4*)(wq + (size_t)o * H_);
    float s = 0.f;
    #pragma unroll
    for (int i = 0; i < 4; ++i) {
        float4 q = q4[lane + i * 64];
        float4 w = w4[lane + i * 64];
        s += q.x * w.x + q.y * w.y + q.z * w.z + q.w * w.w;
    }
    #pragma unroll
    for (int m = 32; m >= 1; m >>= 1) s += __shfl_xor(s, m, 64);
    if (lane == 0) r[b * H_ + o] = s + bias[o];
}

// K3: fused  score[b,v] = sum_o Ws[o]*tanh( (key[b,v,:]·Wk[o,:]) + r[b,o] )
// workgroup: 512 threads (8 waves), tile = (b, 64 v-rows) x (full o=1024 in 4 tiles of 256)
// A tile (key, bf16) resident in LDS for the whole kernel -> key read from HBM once.
__global__ __launch_bounds__(512) void score_kernel(const float* __restrict__ key,
                                                    const unsigned short* __restrict__ wkb,
                                                    const float* __restrict__ r,
                                                    const float* __restrict__ wsc,
                                                    float* __restrict__ score) {
    __shared__ unsigned short Alds[64 * 1032];   // 64 rows, k padded 1024+8 (bank-safe)
    __shared__ unsigned short Blds[256 * 40];    // 256 o-rows, BK=32 padded +8
    __shared__ float scoreLds[64];

    int t = threadIdx.x;
    int b = blockIdx.x >> 6;
    int v0 = (blockIdx.x & 63) << 6;
    int lane = t & 63;
    int wid = t >> 6;
    int waveM = wid >> 2;   // 0..1  (32 v-rows each)
    int waveN = wid & 3;    // 0..3  (64 o-cols each)
    int l15 = lane & 15;
    int l4 = lane >> 4;     // 0..3

    // ---- build resident A tile: key[b, v0..v0+64, 0..1024) -> bf16 LDS
    {
        const float* kbase = key + ((size_t)(b * V_ + v0)) * H_;
        int row = t >> 3;
        int j = t & 7;
        const float4* src = (const float4*)(kbase + (size_t)row * H_);
        unsigned short* dst = Alds + row * 1032;
        #pragma unroll
        for (int it = 0; it < 32; ++it) {
            int c4 = j + it * 8;            // float4 index 0..255 within row
            float4 f = src[c4];
            ushort4 u;
            u.x = f2bf(f.x); u.y = f2bf(f.y); u.z = f2bf(f.z); u.w = f2bf(f.w);
            *(ushort4*)(dst + c4 * 4) = u;
        }
    }
    if (t < 64) scoreLds[t] = 0.f;

    int o_stage = t >> 1;   // 0..255
    int kh = t & 1;

    for (int ot = 0; ot < 4; ++ot) {
        int obase = ot * 256;
        f32x4 acc[2][4];
        #pragma unroll
        for (int mi = 0; mi < 2; ++mi)
            #pragma unroll
            for (int nj = 0; nj < 4; ++nj)
                acc[mi][nj] = (f32x4){0.f, 0.f, 0.f, 0.f};

        for (int kc = 0; kc < 32; ++kc) {
            // issue global loads for B chunk before barrier (overlap with prev compute)
            const uint4* gsrc = (const uint4*)(wkb + (size_t)(obase + o_stage) * H_ + kc * 32 + kh * 16);
            uint4 g0 = gsrc[0];
            uint4 g1 = gsrc[1];
            __syncthreads();
            uint4* bdst = (uint4*)(Blds + o_stage * 40 + kh * 16);
            bdst[0] = g0; bdst[1] = g1;
            __syncthreads();

            bf16x8 af[2];
            #pragma unroll
            for (int mi = 0; mi < 2; ++mi)
                af[mi] = *(const bf16x8*)(Alds + (waveM * 32 + mi * 16 + l15) * 1032 + kc * 32 + l4 * 8);
            #pragma unroll
            for (int nj = 0; nj < 4; ++nj) {
                bf16x8 bf = *(const bf16x8*)(Blds + (waveN * 64 + nj * 16 + l15) * 40 + l4 * 8);
                acc[0][nj] = __builtin_amdgcn_mfma_f32_16x16x32_bf16(af[0], bf, acc[0][nj], 0, 0, 0);
                acc[1][nj] = __builtin_amdgcn_mfma_f32_16x16x32_bf16(af[1], bf, acc[1][nj], 0, 0, 0);
            }
        }

        // epilogue: s += Ws[o]*tanh(C + r[b,o]); C/D layout: col=lane&15, row=l4*4+reg
        float rv[4], wv[4];
        #pragma unroll
        for (int nj = 0; nj < 4; ++nj) {
            int o = obase + waveN * 64 + nj * 16 + l15;
            rv[nj] = r[b * H_ + o];
            wv[nj] = wsc[o];
        }
        #pragma unroll
        for (int mi = 0; mi < 2; ++mi) {
            #pragma unroll
            for (int reg = 0; reg < 4; ++reg) {
                float s = 0.f;
                #pragma unroll
                for (int nj = 0; nj < 4; ++nj) {
                    float x = acc[mi][nj][reg] + rv[nj];
                    float e = __expf(2.f * x);
                    float th = 1.f - 2.f / (e + 1.f);   // tanh, inf-safe
                    s += th * wv[nj];
                }
                #pragma unroll
                for (int m = 1; m < 16; m <<= 1) s += __shfl_xor(s, m, 64);
                if (l15 == 0) {
                    int vl = waveM * 32 + mi * 16 + l4 * 4 + reg;
                    atomicAdd(&scoreLds[vl], s);
                }
            }
        }
    }
    __syncthreads();
    if (t < 64) score[b * V_ + v0 + t] = scoreLds[t];
}

// K4: softmax over V per b  (bs dropped: softmax shift-invariant)
__global__ __launch_bounds__(256) void softmax_kernel(const float* __restrict__ score,
                                                      float* __restrict__ attn) {
    int b = blockIdx.x, t = threadIdx.x;
    __shared__ float red[8];
    const float* s = score + b * V_;
    float v[16];
    float mx = -1e30f;
    #pragma unroll
    for (int i = 0; i < 16; ++i) { v[i] = s[t + i * 256]; mx = fmaxf(mx, v[i]); }
    #pragma unroll
    for (int m = 32; m >= 1; m >>= 1) mx = fmaxf(mx, __shfl_xor(mx, m, 64));
    if ((t & 63) == 0) red[t >> 6] = mx;
    __syncthreads();
    mx = fmaxf(fmaxf(red[0], red[1]), fmaxf(red[2], red[3]));
    float sum = 0.f;
    #pragma unroll
    for (int i = 0; i < 16; ++i) { v[i] = __expf(v[i] - mx); sum += v[i]; }
    #pragma unroll
    for (int m = 32; m >= 1; m >>= 1) sum += __shfl_xor(sum, m, 64);
    if ((t & 63) == 0) red[4 + (t >> 6)] = sum;
    __syncthreads();
    float inv = 1.f / (red[4] + red[5] + red[6] + red[7]);
    float* a = attn + b * V_;
    #pragma unroll
    for (int i = 0; i < 16; ++i) a[t + i * 256] = v[i] * inv;
}

// K5: context[b,h] = sum_v attn[b,v]*value[b,v,h]   (BW-bound stream)
__global__ __launch_bounds__(256) void context_kernel(const float* __restrict__ value,
                                                      const float* __restrict__ attn,
                                                      float* __restrict__ ctx) {
    int b = blockIdx.x, hc = blockIdx.y, vc = blockIdx.z, t = threadIdx.x;
    __shared__ float a[512];
    int vb = vc * 512;
    a[t] = attn[b * V_ + vb + t];
    a[t + 256] = attn[b * V_ + vb + t + 256];
    __syncthreads();
    int h = hc * 256 + t;
    const float* vp = value + ((size_t)(b * V_ + vb)) * H_ + h;
    float acc = 0.f;
    #pragma unroll 8
    for (int i = 0; i < 512; ++i) acc += a[i] * vp[(size_t)i * H_];
    atomicAdd(&ctx[b * H_ + h], acc);
}

extern "C" void kernel_launch(void* const* d_in, const int* in_sizes, int n_in,
                              void* d_out, int out_size, void* d_ws, size_t ws_size,
                              hipStream_t stream) {
    const float* query = (const float*)d_in[0];
    const float* key   = (const float*)d_in[1];
    const float* value = (const float*)d_in[2];
    const float* Wq    = (const float*)d_in[3];
    const float* Wk    = (const float*)d_in[4];
    const float* bias  = (const float*)d_in[5];
    const float* Wsv   = (const float*)d_in[6];
    // d_in[7] = bs : constant shift, cancels in softmax; context unaffected.

    unsigned short* wkb = (unsigned short*)d_ws;                        // 2 MB
    float* r     = (float*)((char*)d_ws + (2u << 20));                  // 128 KB
    float* score = (float*)((char*)d_ws + (2u << 20) + (128u << 10));   // 512 KB

    float* ctx  = (float*)d_out;             // 32*1024
    float* attn = (float*)d_out + 32 * 1024; // 32*4096

    hipMemsetAsync(ctx, 0, 32 * 1024 * sizeof(float), stream);
    wk_to_bf16<<<1024, 256, 0, stream>>>(Wk, wkb);
    compute_r<<<8192, 256, 0, stream>>>(query, Wq, bias, r);
    score_kernel<<<2048, 512, 0, stream>>>(key, wkb, r, Wsv, score);
    softmax_kernel<<<32, 256, 0, stream>>>(score, attn);
    context_kernel<<<dim3(32, 4, 8), 256, 0, stream>>>(value, attn, ctx);
}